// Round 2
// baseline (471.660 us; speedup 1.0000x reference)
//
#include <hip/hip_runtime.h>
#include <math.h>

// Problem constants (from reference)
constexpr int Bc   = 256;      // batch
constexpr int KP1  = 4097;     // K negatives + 1
constexpr int Dc   = 128;      // feature dim
constexpr int NROW = 1000000;  // memory bank rows
constexpr float MOM = 0.5f;
constexpr float Tc  = 0.07f;

constexpr int CAP   = 8;       // per-row index bucket capacity
constexpr int OVCAP = 8192;    // overflow list capacity

// ws int layout: cnt[NROW] | ovcnt[1] | ov[OVCAP] | slots[NROW*CAP]
constexpr size_t WS_CNT    = 0;
constexpr size_t WS_OVCNT  = WS_CNT + NROW;
constexpr size_t WS_OV     = WS_OVCNT + 1;
constexpr size_t WS_SLOTS  = WS_OV + OVCAP;
constexpr size_t WS_NEEDED = (WS_SLOTS + (size_t)NROW * CAP) * sizeof(int);

// ---------------------------------------------------------------------------
// Zero the counters (cnt[NROW] + ovcnt).
__global__ __launch_bounds__(256) void zero_kernel(int* __restrict__ p, int n) {
    int i = blockIdx.x * 256 + threadIdx.x;
    const int stride = gridDim.x * 256;
    for (; i < n; i += stride) p[i] = 0;
}

// ---------------------------------------------------------------------------
// Build inverted index: for each (b,k), append encoded (b<<13|k) to row bucket.
__global__ __launch_bounds__(256) void build_index_kernel(
    const int* __restrict__ idx, int* __restrict__ cnt, int* __restrict__ slots,
    int* __restrict__ ovcnt, int* __restrict__ ov) {
    int i = blockIdx.x * 256 + threadIdx.x;
    const int total = Bc * KP1;
    const int stride = gridDim.x * 256;
    for (; i < total; i += stride) {
        const int row = idx[i];
        const int b = i / KP1;
        const int k = i - b * KP1;
        const int e = (b << 13) | k;
        const int c = atomicAdd(&cnt[row], 1);
        if (c < CAP) {
            slots[(size_t)row * CAP + c] = e;
        } else {
            const int o = atomicAdd(ovcnt, 1);
            if (o < OVCAP) ov[o] = e;
        }
    }
}

// ---------------------------------------------------------------------------
// Fused: stream-copy the bank AND compute dot products for referenced rows.
// Each wave handles 2 rows per iteration (32 lanes x float4 = 512B per row).
__global__ __launch_bounds__(256) void fused_copy_dot_kernel(
    const float* __restrict__ memory,
    const float* __restrict__ ab, const float* __restrict__ l,
    const float* __restrict__ ss,
    const int* __restrict__ cnt, const int* __restrict__ slots,
    float* __restrict__ out, float* __restrict__ out_mem) {
    const int lane = threadIdx.x & 63;
    const int half = lane >> 5;   // which of the wave's 2 rows
    const int sub  = lane & 31;   // float4 index within the row (32*4 = 128)
    const int gw   = blockIdx.x * 4 + (threadIdx.x >> 6);
    const int nw   = gridDim.x * 4;
    const size_t plane = (size_t)Bc * KP1;
    const float invT = 1.0f / Tc;

    for (int rp = gw; rp < NROW / 2; rp += nw) {
        const int row = rp * 2 + half;
        const size_t off = (size_t)row * Dc + sub * 4;
        const float4 w = *(const float4*)(memory + off);
        *(float4*)(out_mem + off) = w;   // copy (y-rows fixed up later)

        int c = cnt[row];
        if (c > CAP) c = CAP;
        for (int j = 0; j < c; ++j) {
            const int e = slots[(size_t)row * CAP + j];
            const int b = e >> 13;
            const int k = e & 8191;
            const float4 qa = *(const float4*)(ab + b * Dc + sub * 4);
            const float4 ql = *(const float4*)(l  + b * Dc + sub * 4);
            const float4 qs = *(const float4*)(ss + b * Dc + sub * 4);
            float sa = w.x * qa.x + w.y * qa.y + w.z * qa.z + w.w * qa.w;
            float sl = w.x * ql.x + w.y * ql.y + w.z * ql.z + w.w * ql.w;
            float s2 = w.x * qs.x + w.y * qs.y + w.z * qs.z + w.w * qs.w;
            // reduce across the 32 lanes of this half (xor<32 stays in-half)
#pragma unroll
            for (int o = 16; o; o >>= 1) {
                sa += __shfl_xor(sa, o);
                sl += __shfl_xor(sl, o);
                s2 += __shfl_xor(s2, o);
            }
            if (sub == 0) {
                const size_t ob = (size_t)b * KP1 + k;
                out[0 * plane + ob] = sa * invT;  // out_orig (ab)
                out[1 * plane + ob] = sl * invT;  // out_l
                out[2 * plane + ob] = s2 * invT;  // out_ss
            }
        }
    }
}

// ---------------------------------------------------------------------------
// Overflow entries (expected ~0-5): one wave per entry, full 64-lane dot.
__global__ __launch_bounds__(64) void overflow_dot_kernel(
    const float* __restrict__ memory,
    const float* __restrict__ ab, const float* __restrict__ l,
    const float* __restrict__ ss, const int* __restrict__ idx,
    const int* __restrict__ ovcnt, const int* __restrict__ ov,
    float* __restrict__ out) {
    int n = *ovcnt;
    if (n > OVCAP) n = OVCAP;
    const int lane = threadIdx.x;
    const size_t plane = (size_t)Bc * KP1;
    const float invT = 1.0f / Tc;
    for (int i = blockIdx.x; i < n; i += gridDim.x) {
        const int e = ov[i];
        const int b = e >> 13;
        const int k = e & 8191;
        const int row = idx[(size_t)b * KP1 + k];
        const float2 w = *(const float2*)(memory + (size_t)row * Dc + lane * 2);
        const float2 qa = *(const float2*)(ab + b * Dc + lane * 2);
        const float2 ql = *(const float2*)(l  + b * Dc + lane * 2);
        const float2 qs = *(const float2*)(ss + b * Dc + lane * 2);
        float sa = w.x * qa.x + w.y * qa.y;
        float sl = w.x * ql.x + w.y * ql.y;
        float s2 = w.x * qs.x + w.y * qs.y;
#pragma unroll
        for (int o = 32; o; o >>= 1) {
            sa += __shfl_xor(sa, o);
            sl += __shfl_xor(sl, o);
            s2 += __shfl_xor(s2, o);
        }
        if (lane == 0) {
            const size_t ob = (size_t)b * KP1 + k;
            out[0 * plane + ob] = sa * invT;
            out[1 * plane + ob] = sl * invT;
            out[2 * plane + ob] = s2 * invT;
        }
    }
}

// ---------------------------------------------------------------------------
// Momentum scatter-update of rows y[b]; last-write-wins for duplicates.
__global__ __launch_bounds__(64) void scatter_kernel(const float* __restrict__ memory,
                                                     const float* __restrict__ ab,
                                                     const int* __restrict__ y,
                                                     float* __restrict__ out_mem) {
    const int b = blockIdx.x;
    const int row = y[b];
    for (int b2 = b + 1; b2 < Bc; ++b2)
        if (y[b2] == row) return;  // a later b writes this row

    const int lane = threadIdx.x;  // 0..63
    float2 m = *(const float2*)(memory + (size_t)row * Dc + lane * 2);
    float2 a = *(const float2*)(ab + b * Dc + lane * 2);
    float v0 = m.x * MOM + a.x * (1.0f - MOM);
    float v1 = m.y * MOM + a.y * (1.0f - MOM);
    float s = v0 * v0 + v1 * v1;
#pragma unroll
    for (int off = 32; off; off >>= 1) s += __shfl_xor(s, off);
    const float inv = 1.0f / sqrtf(s);
    float2 o;
    o.x = v0 * inv;
    o.y = v1 * inv;
    *(float2*)(out_mem + (size_t)row * Dc + lane * 2) = o;
}

// ---------------------------------------------------------------------------
// Fallback path (round-1 proven kernels) if ws is too small.
__global__ __launch_bounds__(256) void copy_mem_kernel(const float4* __restrict__ src,
                                                       float4* __restrict__ dst,
                                                       int n4) {
    int i = blockIdx.x * 256 + threadIdx.x;
    const int stride = gridDim.x * 256;
    for (; i < n4; i += stride) dst[i] = src[i];
}

__global__ __launch_bounds__(256) void gather_dot_kernel(
    const float* __restrict__ memory,
    const float* __restrict__ ab,
    const float* __restrict__ l,
    const float* __restrict__ ss,
    const int* __restrict__ idx,
    float* __restrict__ out) {
    const int b    = blockIdx.x;
    const int lane = threadIdx.x & 63;
    const int wid  = (threadIdx.x >> 6) + (blockIdx.y << 2);
    const int nw   = gridDim.y << 2;
    const int g    = lane >> 3;
    const int sub  = lane & 7;

    float4 qa[4], ql[4], qs[4];
#pragma unroll
    for (int it = 0; it < 4; ++it) {
        const int d = it * 32 + sub * 4;
        qa[it] = *(const float4*)(ab + b * Dc + d);
        ql[it] = *(const float4*)(l + b * Dc + d);
        qs[it] = *(const float4*)(ss + b * Dc + d);
    }
    const int* idxb = idx + (size_t)b * KP1;
    const size_t out_b = (size_t)b * KP1;
    const size_t plane = (size_t)Bc * KP1;

    for (int k0 = wid * 8; k0 < KP1; k0 += nw * 8) {
        const int k = k0 + g;
        const int kc = (k < KP1) ? k : (KP1 - 1);
        const int row = idxb[kc];
        const float* wrow = memory + (size_t)row * Dc;
        float sa = 0.f, sl = 0.f, s2 = 0.f;
#pragma unroll
        for (int it = 0; it < 4; ++it) {
            const float4 w = *(const float4*)(wrow + it * 32 + sub * 4);
            sa += w.x * qa[it].x + w.y * qa[it].y + w.z * qa[it].z + w.w * qa[it].w;
            sl += w.x * ql[it].x + w.y * ql[it].y + w.z * ql[it].z + w.w * ql[it].w;
            s2 += w.x * qs[it].x + w.y * qs[it].y + w.z * qs[it].z + w.w * qs[it].w;
        }
#pragma unroll
        for (int off = 1; off < 8; off <<= 1) {
            sa += __shfl_xor(sa, off);
            sl += __shfl_xor(sl, off);
            s2 += __shfl_xor(s2, off);
        }
        if (sub == 0 && k < KP1) {
            out[0 * plane + out_b + k] = sa / Tc;
            out[1 * plane + out_b + k] = sl / Tc;
            out[2 * plane + out_b + k] = s2 / Tc;
        }
    }
}

// ---------------------------------------------------------------------------
extern "C" void kernel_launch(void* const* d_in, const int* in_sizes, int n_in,
                              void* d_out, int out_size, void* d_ws, size_t ws_size,
                              hipStream_t stream) {
    const float* ab     = (const float*)d_in[0];
    const float* l      = (const float*)d_in[1];
    const float* ss     = (const float*)d_in[2];
    const float* memory = (const float*)d_in[3];
    const int*   idx    = (const int*)d_in[4];
    const int*   y      = (const int*)d_in[5];

    float* out     = (float*)d_out;
    float* out_mem = out + (size_t)3 * Bc * KP1;

    if (ws_size >= WS_NEEDED) {
        int* wsi   = (int*)d_ws;
        int* cnt   = wsi + WS_CNT;
        int* ovcnt = wsi + WS_OVCNT;
        int* ov    = wsi + WS_OV;
        int* slots = wsi + WS_SLOTS;

        zero_kernel<<<dim3(512), dim3(256), 0, stream>>>(cnt, NROW + 1);  // cnt + ovcnt (adjacent)
        build_index_kernel<<<dim3(1024), dim3(256), 0, stream>>>(idx, cnt, slots, ovcnt, ov);
        fused_copy_dot_kernel<<<dim3(2048), dim3(256), 0, stream>>>(
            memory, ab, l, ss, cnt, slots, out, out_mem);
        overflow_dot_kernel<<<dim3(64), dim3(64), 0, stream>>>(
            memory, ab, l, ss, idx, ovcnt, ov, out);
        scatter_kernel<<<dim3(Bc), dim3(64), 0, stream>>>(memory, ab, y, out_mem);
    } else {
        const int n4 = (NROW * Dc) / 4;
        copy_mem_kernel<<<dim3(2048), dim3(256), 0, stream>>>(
            (const float4*)memory, (float4*)out_mem, n4);
        scatter_kernel<<<dim3(Bc), dim3(64), 0, stream>>>(memory, ab, y, out_mem);
        gather_dot_kernel<<<dim3(Bc, 16), dim3(256), 0, stream>>>(memory, ab, l, ss, idx, out);
    }
}

// Round 3
// 352.237 us; speedup vs baseline: 1.3390x; 1.3390x over previous
//
#include <hip/hip_runtime.h>
#include <math.h>

// Problem constants (from reference)
constexpr int Bc   = 256;      // batch
constexpr int KP1  = 4097;     // K negatives + 1
constexpr int Dc   = 128;      // feature dim
constexpr int NROW = 1000000;  // memory bank rows
constexpr float MOM = 0.5f;
constexpr float Tc  = 0.07f;

// Role split: blocks [0, NCOPY) stream-copy the bank; blocks [NCOPY, NCOPY+NGATH)
// do the gather-dot. 1024 blocks total = 4 blocks/CU -> co-resident, so both
// roles execute concurrently and share HBM bandwidth.
constexpr int NCOPY = 512;
constexpr int NGATH = 512;   // 2 blocks per batch row b

__global__ __launch_bounds__(256) void combo_kernel(
    const float* __restrict__ memory,
    const float* __restrict__ ab,
    const float* __restrict__ l,
    const float* __restrict__ ss,
    const int* __restrict__ idx,
    float* __restrict__ out,
    float* __restrict__ out_mem) {
    if (blockIdx.x < NCOPY) {
        // ---- copy role: 512 MB read + 512 MB write, 4-way unrolled ----
        const float4* __restrict__ src = (const float4*)memory;
        float4* __restrict__ dst = (float4*)out_mem;
        const int n4 = NROW * Dc / 4;          // 32M float4
        const int S  = NCOPY * 256;            // threads in copy role
        int i = blockIdx.x * 256 + threadIdx.x;
        // n4 / S = 244.14 -> 61 full 4-strided iterations cover 244*S, tail after
        for (; i + 3 * S < n4; i += 4 * S) {
            float4 a0 = src[i];
            float4 a1 = src[i + S];
            float4 a2 = src[i + 2 * S];
            float4 a3 = src[i + 3 * S];
            dst[i]         = a0;
            dst[i + S]     = a1;
            dst[i + 2 * S] = a2;
            dst[i + 3 * S] = a3;
        }
        for (; i < n4; i += S) dst[i] = src[i];
    } else {
        // ---- gather-dot role: 8 lanes per (b,k), queries preloaded ----
        const int gb   = blockIdx.x - NCOPY;   // 0..511
        const int b    = gb >> 1;              // 2 blocks per b
        const int lane = threadIdx.x & 63;
        const int wid  = ((gb & 1) << 2) + (threadIdx.x >> 6);  // 0..7
        const int nw   = 8;
        const int g    = lane >> 3;  // k-group 0..7
        const int sub  = lane & 7;   // lane within group

        float4 qa[4], ql[4], qs[4];
#pragma unroll
        for (int it = 0; it < 4; ++it) {
            const int d = it * 32 + sub * 4;
            qa[it] = *(const float4*)(ab + b * Dc + d);
            ql[it] = *(const float4*)(l  + b * Dc + d);
            qs[it] = *(const float4*)(ss + b * Dc + d);
        }
        const int* idxb = idx + (size_t)b * KP1;
        const size_t out_b = (size_t)b * KP1;
        const size_t plane = (size_t)Bc * KP1;
        const float invT = 1.0f / Tc;

        for (int k0 = wid * 8; k0 < KP1; k0 += nw * 8) {
            const int k = k0 + g;
            const int kc = (k < KP1) ? k : (KP1 - 1);  // clamp; masked on write
            const int row = idxb[kc];
            const float* wrow = memory + (size_t)row * Dc;
            float sa = 0.f, sl = 0.f, s2 = 0.f;
#pragma unroll
            for (int it = 0; it < 4; ++it) {
                const float4 w = *(const float4*)(wrow + it * 32 + sub * 4);
                sa += w.x * qa[it].x + w.y * qa[it].y + w.z * qa[it].z + w.w * qa[it].w;
                sl += w.x * ql[it].x + w.y * ql[it].y + w.z * ql[it].z + w.w * ql[it].w;
                s2 += w.x * qs[it].x + w.y * qs[it].y + w.z * qs[it].z + w.w * qs[it].w;
            }
#pragma unroll
            for (int off = 1; off < 8; off <<= 1) {
                sa += __shfl_xor(sa, off);
                sl += __shfl_xor(sl, off);
                s2 += __shfl_xor(s2, off);
            }
            if (sub == 0 && k < KP1) {
                out[0 * plane + out_b + k] = sa * invT;  // out_orig (ab)
                out[1 * plane + out_b + k] = sl * invT;  // out_l
                out[2 * plane + out_b + k] = s2 * invT;  // out_ss
            }
        }
    }
}

// ---------------------------------------------------------------------------
// Momentum scatter-update of rows y[b]; runs AFTER combo so it overwrites the
// copied rows. Last-write-wins for duplicate y (numpy scatter semantics).
__global__ __launch_bounds__(64) void scatter_kernel(const float* __restrict__ memory,
                                                     const float* __restrict__ ab,
                                                     const int* __restrict__ y,
                                                     float* __restrict__ out_mem) {
    const int b = blockIdx.x;
    const int row = y[b];
    for (int b2 = b + 1; b2 < Bc; ++b2)
        if (y[b2] == row) return;  // a later b writes this row

    const int lane = threadIdx.x;  // 0..63
    float2 m = *(const float2*)(memory + (size_t)row * Dc + lane * 2);
    float2 a = *(const float2*)(ab + b * Dc + lane * 2);
    float v0 = m.x * MOM + a.x * (1.0f - MOM);
    float v1 = m.y * MOM + a.y * (1.0f - MOM);
    float s = v0 * v0 + v1 * v1;
#pragma unroll
    for (int off = 32; off; off >>= 1) s += __shfl_xor(s, off);
    const float inv = 1.0f / sqrtf(s);
    float2 o;
    o.x = v0 * inv;
    o.y = v1 * inv;
    *(float2*)(out_mem + (size_t)row * Dc + lane * 2) = o;
}

// ---------------------------------------------------------------------------
extern "C" void kernel_launch(void* const* d_in, const int* in_sizes, int n_in,
                              void* d_out, int out_size, void* d_ws, size_t ws_size,
                              hipStream_t stream) {
    const float* ab     = (const float*)d_in[0];
    const float* l      = (const float*)d_in[1];
    const float* ss     = (const float*)d_in[2];
    const float* memory = (const float*)d_in[3];
    const int*   idx    = (const int*)d_in[4];
    const int*   y      = (const int*)d_in[5];

    float* out     = (float*)d_out;
    float* out_mem = out + (size_t)3 * Bc * KP1;

    combo_kernel<<<dim3(NCOPY + NGATH), dim3(256), 0, stream>>>(
        memory, ab, l, ss, idx, out, out_mem);
    scatter_kernel<<<dim3(Bc), dim3(64), 0, stream>>>(memory, ab, y, out_mem);
}

// Round 5
// 302.336 us; speedup vs baseline: 1.5601x; 1.1651x over previous
//
#include <hip/hip_runtime.h>
#include <math.h>

// Problem constants (from reference)
constexpr int Bc   = 256;      // batch
constexpr int KP1  = 4097;     // K negatives + 1
constexpr int Dc   = 128;      // feature dim
constexpr int NROW = 1000000;  // memory bank rows
constexpr float MOM = 0.5f;
constexpr float Tc  = 0.07f;

// clang-native float4 — __builtin_nontemporal_store rejects HIP_vector_type
typedef float f4 __attribute__((ext_vector_type(4)));

// ---------------------------------------------------------------------------
// Phase A: stream-copy the bank. Nontemporal stores keep L3 populated with
// bank READ lines only, so the gather phase sees a warmer L3.
__global__ __launch_bounds__(256) void copy_mem_kernel(const f4* __restrict__ src,
                                                       f4* __restrict__ dst,
                                                       int n4) {
    int i = blockIdx.x * 256 + threadIdx.x;
    const int S = gridDim.x * 256;
    for (; i + 3 * S < n4; i += 4 * S) {
        f4 a0 = src[i];
        f4 a1 = src[i + S];
        f4 a2 = src[i + 2 * S];
        f4 a3 = src[i + 3 * S];
        __builtin_nontemporal_store(a0, &dst[i]);
        __builtin_nontemporal_store(a1, &dst[i + S]);
        __builtin_nontemporal_store(a2, &dst[i + 2 * S]);
        __builtin_nontemporal_store(a3, &dst[i + 3 * S]);
    }
    for (; i < n4; i += S) __builtin_nontemporal_store(src[i], &dst[i]);
}

// ---------------------------------------------------------------------------
// Momentum scatter-update of rows y[b]; overwrites copied rows.
// Last-write-wins for duplicate y (numpy scatter semantics).
__global__ __launch_bounds__(64) void scatter_kernel(const float* __restrict__ memory,
                                                     const float* __restrict__ ab,
                                                     const int* __restrict__ y,
                                                     float* __restrict__ out_mem) {
    const int b = blockIdx.x;
    const int row = y[b];
    for (int b2 = b + 1; b2 < Bc; ++b2)
        if (y[b2] == row) return;  // a later b writes this row

    const int lane = threadIdx.x;  // 0..63
    float2 m = *(const float2*)(memory + (size_t)row * Dc + lane * 2);
    float2 a = *(const float2*)(ab + b * Dc + lane * 2);
    float v0 = m.x * MOM + a.x * (1.0f - MOM);
    float v1 = m.y * MOM + a.y * (1.0f - MOM);
    float s = v0 * v0 + v1 * v1;
#pragma unroll
    for (int off = 32; off; off >>= 1) s += __shfl_xor(s, off);
    const float inv = 1.0f / sqrtf(s);
    float2 o;
    o.x = v0 * inv;
    o.y = v1 * inv;
    *(float2*)(out_mem + (size_t)row * Dc + lane * 2) = o;
}

// ---------------------------------------------------------------------------
// Phase B: gather + 3 fused dot products. 8 lanes per (b,k); all row indices
// for this wave's (at most 5) iterations are loaded upfront so row loads of
// iteration t+1 can issue while iteration t reduces (vmcnt vs lgkmcnt are
// independent counters).
constexpr int GY    = 32;            // gridDim.y
constexpr int NW    = GY * 4;        // waves per batch row b (128)
constexpr int KSTEP = NW * 8;        // k covered per iteration (1024)
constexpr int NITER = (KP1 + KSTEP - 1) / KSTEP;  // 5

__global__ __launch_bounds__(256) void gather_dot_kernel(
    const float* __restrict__ memory,
    const float* __restrict__ ab,
    const float* __restrict__ l,
    const float* __restrict__ ss,
    const int* __restrict__ idx,
    float* __restrict__ out) {
    const int b    = blockIdx.x;
    const int lane = threadIdx.x & 63;
    const int wid  = (threadIdx.x >> 6) + (blockIdx.y << 2);  // 0..NW-1
    const int g    = lane >> 3;  // k-group 0..7
    const int sub  = lane & 7;   // lane within group

    // preload queries: lane needs float4 at d = it*32 + sub*4
    float4 qa[4], ql[4], qs[4];
#pragma unroll
    for (int it = 0; it < 4; ++it) {
        const int d = it * 32 + sub * 4;
        qa[it] = *(const float4*)(ab + b * Dc + d);
        ql[it] = *(const float4*)(l  + b * Dc + d);
        qs[it] = *(const float4*)(ss + b * Dc + d);
    }
    const int* idxb = idx + (size_t)b * KP1;
    const size_t out_b = (size_t)b * KP1;
    const size_t plane = (size_t)Bc * KP1;
    const float invT = 1.0f / Tc;
    const int kbase = wid * 8 + g;

    // all row indices upfront (idx loads are L2-hot, latency hidden once)
    int rows[NITER];
#pragma unroll
    for (int t = 0; t < NITER; ++t) {
        int k = kbase + t * KSTEP;
        rows[t] = idxb[(k < KP1) ? k : (KP1 - 1)];
    }

#pragma unroll
    for (int t = 0; t < NITER; ++t) {
        const int k = kbase + t * KSTEP;
        const float* wrow = memory + (size_t)rows[t] * Dc;
        float sa = 0.f, sl = 0.f, s2 = 0.f;
#pragma unroll
        for (int it = 0; it < 4; ++it) {
            const float4 w = *(const float4*)(wrow + it * 32 + sub * 4);
            sa += w.x * qa[it].x + w.y * qa[it].y + w.z * qa[it].z + w.w * qa[it].w;
            sl += w.x * ql[it].x + w.y * ql[it].y + w.z * ql[it].z + w.w * ql[it].w;
            s2 += w.x * qs[it].x + w.y * qs[it].y + w.z * qs[it].z + w.w * qs[it].w;
        }
#pragma unroll
        for (int off = 1; off < 8; off <<= 1) {
            sa += __shfl_xor(sa, off);
            sl += __shfl_xor(sl, off);
            s2 += __shfl_xor(s2, off);
        }
        if (sub == 0 && k < KP1) {
            out[0 * plane + out_b + k] = sa * invT;  // out_orig (ab)
            out[1 * plane + out_b + k] = sl * invT;  // out_l
            out[2 * plane + out_b + k] = s2 * invT;  // out_ss
        }
    }
}

// ---------------------------------------------------------------------------
extern "C" void kernel_launch(void* const* d_in, const int* in_sizes, int n_in,
                              void* d_out, int out_size, void* d_ws, size_t ws_size,
                              hipStream_t stream) {
    const float* ab     = (const float*)d_in[0];
    const float* l      = (const float*)d_in[1];
    const float* ss     = (const float*)d_in[2];
    const float* memory = (const float*)d_in[3];
    const int*   idx    = (const int*)d_in[4];
    const int*   y      = (const int*)d_in[5];

    float* out     = (float*)d_out;
    float* out_mem = out + (size_t)3 * Bc * KP1;

    const int n4 = (NROW * Dc) / 4;  // 32M float4
    copy_mem_kernel<<<dim3(4096), dim3(256), 0, stream>>>(
        (const f4*)memory, (f4*)out_mem, n4);
    scatter_kernel<<<dim3(Bc), dim3(64), 0, stream>>>(memory, ab, y, out_mem);
    gather_dot_kernel<<<dim3(Bc, GY), dim3(256), 0, stream>>>(memory, ab, l, ss, idx, out);
}